// Round 10
// baseline (124.549 us; speedup 1.0000x reference)
//
#include <hip/hip_runtime.h>

typedef float    f32x4  __attribute__((ext_vector_type(4)));
typedef _Float16 half8  __attribute__((ext_vector_type(8)));
typedef _Float16 half4v __attribute__((ext_vector_type(4)));

#define MFMA16(a,b,c) __builtin_amdgcn_mfma_f32_16x16x32_f16(a,b,c,0,0,0)

__device__ __forceinline__ float exp2_fast(float x){
  float y; asm("v_exp_f32 %0, %1" : "=v"(y) : "v"(x)); return y;
}
// async global->LDS, 16B per lane; LDS dest is wave-uniform base + lane*16
__device__ __forceinline__ void gload_lds16(const _Float16* g, _Float16* l){
  __builtin_amdgcn_global_load_lds(
      (const __attribute__((address_space(1))) unsigned int*)(g),
      (__attribute__((address_space(3))) unsigned int*)(l),
      16, 0, 0);
}

#define S_LEN 2048
#define E_DIM 1024
#define H_NUM 16
#define D_DIM 64
#define NBH   32
#define M_ROWS 4096
#define N3    3072
#define LOG2E 1.44269504089f

// ---------------- prep: fp32 -> fp16 cast ----------------
__global__ void cast_x_kernel(const float* __restrict__ in,
                              _Float16* __restrict__ hi, int n4){
  int i = blockIdx.x * 256 + threadIdx.x;
  if (i >= n4) return;
  const float4 v = reinterpret_cast<const float4*>(in)[i];
  half4v h;
  h[0] = (_Float16)v.x; h[1] = (_Float16)v.y;
  h[2] = (_Float16)v.z; h[3] = (_Float16)v.w;
  *reinterpret_cast<half4v*>(&hi[i*4]) = h;
}

// out[n][k] = in[k][n], single fp16. in is R x C, out is C x R.
__global__ void transpose_half(const float* __restrict__ in,
                               _Float16* __restrict__ hi, int R, int C){
  __shared__ float tile[32][33];
  int bx = blockIdx.x * 32, by = blockIdx.y * 32;
  int tx = threadIdx.x & 31, ty = threadIdx.x >> 5;   // 256 threads = 32x8
#pragma unroll
  for (int i = ty; i < 32; i += 8)
    tile[i][tx] = in[(size_t)(by + i) * C + bx + tx];
  __syncthreads();
#pragma unroll
  for (int i = ty; i < 32; i += 8)
    hi[(size_t)(bx + i) * R + by + tx] = (_Float16)tile[tx][i];
}

// ---------------- fp16 GEMM (m97 structure + T2 swizzle) --------------------
// C = A @ B^T(rowmajor N x K). 128x128 tile, BK=64, 4 waves, global_load_lds
// staging; LDS dest linear, global source col inverse-XOR-swizzled, reads
// XOR-swizzled (rule #21) -> b128 reads at the 8-lane/quad structural floor.
template<int EPI>
__global__ __launch_bounds__(256, 3) void gemm97(
    const _Float16* __restrict__ A, const _Float16* __restrict__ B,
    int Kdim, int Ndim, float* __restrict__ Cout,
    _Float16* __restrict__ qh, _Float16* __restrict__ kh, _Float16* __restrict__ vh)
{
  __shared__ __align__(16) _Float16 sA[128][64], sB[128][64];
  const int tid = threadIdx.x;
  const int m0 = blockIdx.y * 128, n0 = blockIdx.x * 128;
  const int wid = tid >> 6, lane = tid & 63;
  const int wr = (wid >> 1) * 64, wc = (wid & 1) * 64;
  const int lr = lane & 15, lc = lane >> 4;
  const int ldrow = lane >> 3;                        // 0..7 within chunk
  const int ldcol = ((lane & 7) ^ ldrow) * 8;         // inverse-swizzled source col
  const int swz = (lr & 7) << 4;                      // byte XOR for reads

  f32x4 acc[4][4] = {};
  const int nK = Kdim >> 6;
  for (int ks = 0; ks < nK; ++ks){
    const int k0 = ks << 6;
#pragma unroll
    for (int cc = 0; cc < 4; ++cc){
      const int c = wid * 4 + cc;
      const int row = c * 8 + ldrow;
      gload_lds16(&A[(size_t)(m0 + row) * Kdim + k0 + ldcol], &sA[c*8][0]);
      gload_lds16(&B[(size_t)(n0 + row) * Kdim + k0 + ldcol], &sB[c*8][0]);
    }
    __syncthreads();
    const char* ab = (const char*)&sA[0][0];
    const char* bb = (const char*)&sB[0][0];
#pragma unroll
    for (int kk = 0; kk < 64; kk += 32){
      half8 fa[4], fb[4];
#pragma unroll
      for (int t = 0; t < 4; ++t){
        fa[t] = *reinterpret_cast<const half8*>(
            ab + (wr + t*16 + lr)*128 + ((kk*2 + lc*16) ^ swz));
        fb[t] = *reinterpret_cast<const half8*>(
            bb + (wc + t*16 + lr)*128 + ((kk*2 + lc*16) ^ swz));
      }
#pragma unroll
      for (int mt = 0; mt < 4; ++mt)
#pragma unroll
        for (int nt = 0; nt < 4; ++nt)
          acc[mt][nt] = MFMA16(fa[mt], fb[nt], acc[mt][nt]);
    }
    __syncthreads();
  }
#pragma unroll
  for (int mt = 0; mt < 4; ++mt)
#pragma unroll
    for (int nt = 0; nt < 4; ++nt)
#pragma unroll
      for (int r = 0; r < 4; ++r){
        const int m = m0 + wr + mt*16 + lc*4 + r;
        const int n = n0 + wc + nt*16 + lr;
        float v = acc[mt][nt][r];
        if (EPI == 0){
          Cout[(size_t)m * Ndim + n] = v;
        } else {
          const int t = n >> 10, rem = n & 1023, hh = rem >> 6, d = rem & 63;
          const int b = m >> 11, s = m & 2047;
          const int bh = b * H_NUM + hh;
          if (t == 0) v *= (0.125f * LOG2E);  // fold 1/sqrt(64) and log2(e) into Q
          size_t o;
          if (t == 2)  o = ((size_t)bh * D_DIM + d) * S_LEN + s;   // V transposed
          else         o = ((size_t)bh * S_LEN + s) * D_DIM + d;
          _Float16* ph = (t == 0) ? qh : (t == 1) ? kh : vh;
          ph[o] = (_Float16)v;
        }
      }
}

// ---------------- flash attention, transposed-QK in-register softmax ----------
// Grid 32x32, one q-tile per block, 3 blocks/CU. XCD-aware remap: each XCD
// serves bh in {xcd, xcd+8, xcd+16, xcd+24} (2MB K/V -> L2-resident). qt uses a
// balanced permutation so every CU's 4 blocks sum to exactly 66 KV-iterations.
__global__ __launch_bounds__(256, 3) void attn_kernel(
    const _Float16* __restrict__ Qh, const _Float16* __restrict__ Kh,
    const _Float16* __restrict__ Vth, _Float16* __restrict__ Ao)
{
  __shared__ __align__(16) _Float16 sK[2][64][64], sV[2][64][64];
  __shared__ __align__(16) _Float16 sP[4][16][72];   // per-wave P [q][k], pad 72
  const int tid = threadIdx.x, wid = tid >> 6, lane = tid & 63;
  const int id  = blockIdx.x + 32 * blockIdx.y;
  const int xcd = id & 7, seq = id >> 3;
  const int bh  = xcd + 8 * (seq & 3);
  // balanced qt permutation: CU j gets g in {j',j'+8,j'+16,j'+24}; sums = 62.
  const int g = seq >> 2, hsel = g & 7, bsel = g >> 3;
  const int qt = (bsel == 0) ? 31 - hsel
               : (bsel == 1) ? hsel
               : (bsel == 2) ? 23 - hsel
                             : 8 + hsel;
  const int q0 = qt * 64;
  const int nT = qt + 1;
  const int lr = lane & 15, lc = lane >> 4;
  const int swz = (lr & 7) << 4;        // byte XOR for swizzled fragment reads
  const size_t base = (size_t)bh * S_LEN * D_DIM;

  // staging geometry: wave w stages chunks {2w,2w+1} (8 rows each) of K and V
  const int lrow = lane >> 3;                       // 0..7
  const int cswz = ((lane & 7) ^ lrow) * 8;         // inverse-swizzled source col (halfs)

  auto stage = [&](int t, int b){
    const int kv0 = t * 64;
#pragma unroll
    for (int cc = 0; cc < 2; ++cc){
      const int c = wid * 2 + cc;
      const int row = c * 8 + lrow;
      gload_lds16(&Kh[base + (size_t)(kv0 + row) * D_DIM + cswz], &sK[b][c*8][0]);
      gload_lds16(&Vth[base + (size_t)row * S_LEN + kv0 + cswz], &sV[b][c*8][0]);
    }
  };

  const int b = bh >> 4, hh = bh & 15;

  // Q fragments (B-operand), hoisted; Q already scaled by log2e/8
  half8 fq[2];
  {
    const int qrow = q0 + wid*16 + lr;
#pragma unroll
    for (int kc = 0; kc < 2; ++kc)
      fq[kc] = *reinterpret_cast<const half8*>(&Qh[base + (size_t)qrow * 64 + kc*32 + lc*8]);
  }

  f32x4 acc[4] = {};
  float m = -1e30f, l = 0.f, tm = -1e30f;   // per-lane stats for q = lr

  stage(0, 0);
  __syncthreads();

  int cur = 0;
  for (int t = 0; t < nT; ++t){
    if (t + 1 < nT) stage(t + 1, cur ^ 1);   // async loads hide under compute

    // ST = K·Q^T: lane holds q=lr (col), k = nt*16 + lc*4 + r (row)
    const char* kb = (const char*)&sK[cur][0][0];
    f32x4 sc[4];
    __builtin_amdgcn_s_setprio(1);
#pragma unroll
    for (int nt = 0; nt < 4; ++nt){
      f32x4 z = {};
#pragma unroll
      for (int kc = 0; kc < 2; ++kc){
        const half8 fk = *reinterpret_cast<const half8*>(
            kb + (nt*16 + lr)*128 + ((kc*64 + lc*16) ^ swz));
        z = MFMA16(fk, fq[kc], z);
      }
      sc[nt] = z;
    }
    __builtin_amdgcn_s_setprio(0);

    if (t == qt){   // diagonal: mask k > q
#pragma unroll
      for (int nt = 0; nt < 4; ++nt)
#pragma unroll
        for (int r = 0; r < 4; ++r)
          if (nt*16 + lc*4 + r > wid*16 + lr) sc[nt][r] = -1e30f;
    }

    // in-lane max over 16 + 2 cross-lane hops (lanes lr, lr+16, lr+32, lr+48)
    f32x4 a;
#pragma unroll
    for (int j = 0; j < 4; ++j)
      a[j] = fmaxf(fmaxf(sc[0][j], sc[1][j]), fmaxf(sc[2][j], sc[3][j]));
    float mx = fmaxf(fmaxf(a[0], a[1]), fmaxf(a[2], a[3]));
    mx = fmaxf(mx, __shfl_xor(mx, 16));
    mx = fmaxf(mx, __shfl_xor(mx, 32));
    tm = fmaxf(tm, mx);

    if (__any(mx > m + 8.0f)){   // defer-max THR=8 (log2 units)
      const float mn = fmaxf(m, mx);
      const float s = exp2_fast(m - mn);
      l *= s; m = mn;
      float rs[4];
#pragma unroll
      for (int r = 0; r < 4; ++r)
        rs[r] = __shfl(s, (lc << 4) | (lc*4 + r), 64);
#pragma unroll
      for (int dt = 0; dt < 4; ++dt)
#pragma unroll
        for (int r = 0; r < 4; ++r) acc[dt][r] *= rs[r];
    }

    // P = exp2(sc - m); in-lane sum + 2 hops
    f32x4 ssum = {};
#pragma unroll
    for (int nt = 0; nt < 4; ++nt){
#pragma unroll
      for (int r = 0; r < 4; ++r) sc[nt][r] = exp2_fast(sc[nt][r] - m);
      ssum += sc[nt];
    }
    float s1 = (ssum[0] + ssum[1]) + (ssum[2] + ssum[3]);
    s1 += __shfl_xor(s1, 16);
    s1 += __shfl_xor(s1, 32);
    l += s1;

    // pack P pairs -> 4 x ds_write_b64 of consecutive k (k = 16nt + 4lc + 0..3)
#pragma unroll
    for (int nt = 0; nt < 4; ++nt){
      int2 pk;
      pk.x = __builtin_bit_cast(int, __builtin_amdgcn_cvt_pkrtz(sc[nt][0], sc[nt][1]));
      pk.y = __builtin_bit_cast(int, __builtin_amdgcn_cvt_pkrtz(sc[nt][2], sc[nt][3]));
      *reinterpret_cast<int2*>(&sP[wid][lr][nt*16 + lc*4]) = pk;
    }

    // PV: pa is the A-fragment (row q=lr, k = kc*32 + lc*8 + j)
    const half8 pa0 = *reinterpret_cast<const half8*>(&sP[wid][lr][lc*8]);
    const half8 pa1 = *reinterpret_cast<const half8*>(&sP[wid][lr][32 + lc*8]);
    const char* vb = (const char*)&sV[cur][0][0];
    __builtin_amdgcn_s_setprio(1);
#pragma unroll
    for (int dt = 0; dt < 4; ++dt){
#pragma unroll
      for (int kc = 0; kc < 2; ++kc){
        const half8 fv = *reinterpret_cast<const half8*>(
            vb + (dt*16 + lr)*128 + ((kc*64 + lc*16) ^ swz));
        acc[dt] = MFMA16(kc ? pa1 : pa0, fv, acc[dt]);
      }
    }
    __builtin_amdgcn_s_setprio(0);

    __syncthreads();   // drains next-tile gloads; guards buffer swap
    cur ^= 1;
  }

  // finalize: ghost term = 2^(truemax - m); denom broadcast per q-row
  const float den = l + exp2_fast(tm - m);
  float rden[4];
#pragma unroll
  for (int r = 0; r < 4; ++r)
    rden[r] = __shfl(den, (lc << 4) | (lc*4 + r), 64);
#pragma unroll
  for (int dt = 0; dt < 4; ++dt)
#pragma unroll
    for (int r = 0; r < 4; ++r){
      const float o = acc[dt][r] / rden[r];
      const int q = q0 + wid*16 + lc*4 + r;
      const int d = dt*16 + lr;
      Ao[((size_t)(b*S_LEN + q)) * E_DIM + hh*D_DIM + d] = (_Float16)o;
    }
}

// ---------------- launch ----------------
extern "C" void kernel_launch(void* const* d_in, const int* in_sizes, int n_in,
                              void* d_out, int out_size, void* d_ws, size_t ws_size,
                              hipStream_t stream){
  const float* X    = (const float*)d_in[0];
  const float* Wqkv = (const float*)d_in[1];
  const float* Wo   = (const float*)d_in[2];
  float* out = (float*)d_out;

  _Float16* w = (_Float16*)d_ws;
  size_t off = 0;
  auto alloc = [&](size_t n){ _Float16* p = w + off; off += n; return p; };
  const size_t ME   = (size_t)M_ROWS * E_DIM;
  const size_t WQ   = (size_t)N3 * E_DIM;
  const size_t WOsz = (size_t)E_DIM * E_DIM;
  const size_t QK   = (size_t)NBH * S_LEN * D_DIM;
  _Float16 *Xh = alloc(ME);
  _Float16 *Wqh = alloc(WQ);
  _Float16 *Woh = alloc(WOsz);
  _Float16 *Qh = alloc(QK), *Kh = alloc(QK), *Vth = alloc(QK);
  _Float16 *Ahalf = alloc(ME);

  cast_x_kernel<<<(int)(ME/4/256), 256, 0, stream>>>(X, Xh, (int)(ME/4));
  transpose_half<<<dim3(N3/32, E_DIM/32), 256, 0, stream>>>(Wqkv, Wqh, E_DIM, N3);
  transpose_half<<<dim3(E_DIM/32, E_DIM/32), 256, 0, stream>>>(Wo, Woh, E_DIM, E_DIM);

  gemm97<1><<<dim3(N3/128, M_ROWS/128), 256, 0, stream>>>(
      Xh, Wqh, E_DIM, N3, nullptr, Qh, Kh, Vth);

  attn_kernel<<<dim3(32, NBH), 256, 0, stream>>>(Qh, Kh, Vth, Ahalf);

  gemm97<0><<<dim3(E_DIM/128, M_ROWS/128), 256, 0, stream>>>(
      Ahalf, Woh, E_DIM, E_DIM, out, nullptr, nullptr, nullptr);
}

// Round 12
// 124.291 us; speedup vs baseline: 1.0021x; 1.0021x over previous
//
#include <hip/hip_runtime.h>

typedef float    f32x4  __attribute__((ext_vector_type(4)));
typedef _Float16 half8  __attribute__((ext_vector_type(8)));
typedef _Float16 half4v __attribute__((ext_vector_type(4)));

#define MFMA16(a,b,c) __builtin_amdgcn_mfma_f32_16x16x32_f16(a,b,c,0,0,0)

__device__ __forceinline__ float exp2_fast(float x){
  float y; asm("v_exp_f32 %0, %1" : "=v"(y) : "v"(x)); return y;
}
// async global->LDS, 16B per lane; LDS dest is wave-uniform base + lane*16
__device__ __forceinline__ void gload_lds16(const _Float16* g, _Float16* l){
  __builtin_amdgcn_global_load_lds(
      (const __attribute__((address_space(1))) unsigned int*)(g),
      (__attribute__((address_space(3))) unsigned int*)(l),
      16, 0, 0);
}

#define S_LEN 2048
#define E_DIM 1024
#define H_NUM 16
#define D_DIM 64
#define NBH   32
#define M_ROWS 4096
#define N3    3072
#define LOG2E 1.44269504089f

// ---------------- prep: fp32 -> fp16 cast ----------------
__global__ void cast_x_kernel(const float* __restrict__ in,
                              _Float16* __restrict__ hi, int n4){
  int i = blockIdx.x * 256 + threadIdx.x;
  if (i >= n4) return;
  const float4 v = reinterpret_cast<const float4*>(in)[i];
  half4v h;
  h[0] = (_Float16)v.x; h[1] = (_Float16)v.y;
  h[2] = (_Float16)v.z; h[3] = (_Float16)v.w;
  *reinterpret_cast<half4v*>(&hi[i*4]) = h;
}

// out[n][k] = in[k][n], single fp16. in is R x C, out is C x R.
__global__ void transpose_half(const float* __restrict__ in,
                               _Float16* __restrict__ hi, int R, int C){
  __shared__ float tile[32][33];
  int bx = blockIdx.x * 32, by = blockIdx.y * 32;
  int tx = threadIdx.x & 31, ty = threadIdx.x >> 5;   // 256 threads = 32x8
#pragma unroll
  for (int i = ty; i < 32; i += 8)
    tile[i][tx] = in[(size_t)(by + i) * C + bx + tx];
  __syncthreads();
#pragma unroll
  for (int i = ty; i < 32; i += 8)
    hi[(size_t)(bx + i) * R + by + tx] = (_Float16)tile[tx][i];
}

// ---------------- fp16 GEMM (m97 structure + T2 swizzle) --------------------
// C = A @ B^T(rowmajor N x K). 128x128 tile, BK=64, 4 waves, global_load_lds
// staging; LDS dest linear, global source col inverse-XOR-swizzled, reads
// XOR-swizzled (rule #21) -> b128 reads at the 8-lane/quad structural floor.
template<int EPI>
__global__ __launch_bounds__(256, 3) void gemm97(
    const _Float16* __restrict__ A, const _Float16* __restrict__ B,
    int Kdim, int Ndim, float* __restrict__ Cout,
    _Float16* __restrict__ qh, _Float16* __restrict__ kh, _Float16* __restrict__ vh)
{
  __shared__ __align__(16) _Float16 sA[128][64], sB[128][64];
  const int tid = threadIdx.x;
  const int m0 = blockIdx.y * 128, n0 = blockIdx.x * 128;
  const int wid = tid >> 6, lane = tid & 63;
  const int wr = (wid >> 1) * 64, wc = (wid & 1) * 64;
  const int lr = lane & 15, lc = lane >> 4;
  const int ldrow = lane >> 3;                        // 0..7 within chunk
  const int ldcol = ((lane & 7) ^ ldrow) * 8;         // inverse-swizzled source col
  const int swz = (lr & 7) << 4;                      // byte XOR for reads

  f32x4 acc[4][4] = {};
  const int nK = Kdim >> 6;
  for (int ks = 0; ks < nK; ++ks){
    const int k0 = ks << 6;
#pragma unroll
    for (int cc = 0; cc < 4; ++cc){
      const int c = wid * 4 + cc;
      const int row = c * 8 + ldrow;
      gload_lds16(&A[(size_t)(m0 + row) * Kdim + k0 + ldcol], &sA[c*8][0]);
      gload_lds16(&B[(size_t)(n0 + row) * Kdim + k0 + ldcol], &sB[c*8][0]);
    }
    __syncthreads();
    const char* ab = (const char*)&sA[0][0];
    const char* bb = (const char*)&sB[0][0];
#pragma unroll
    for (int kk = 0; kk < 64; kk += 32){
      half8 fa[4], fb[4];
#pragma unroll
      for (int t = 0; t < 4; ++t){
        fa[t] = *reinterpret_cast<const half8*>(
            ab + (wr + t*16 + lr)*128 + ((kk*2 + lc*16) ^ swz));
        fb[t] = *reinterpret_cast<const half8*>(
            bb + (wc + t*16 + lr)*128 + ((kk*2 + lc*16) ^ swz));
      }
#pragma unroll
      for (int mt = 0; mt < 4; ++mt)
#pragma unroll
        for (int nt = 0; nt < 4; ++nt)
          acc[mt][nt] = MFMA16(fa[mt], fb[nt], acc[mt][nt]);
    }
    __syncthreads();
  }
#pragma unroll
  for (int mt = 0; mt < 4; ++mt)
#pragma unroll
    for (int nt = 0; nt < 4; ++nt)
#pragma unroll
      for (int r = 0; r < 4; ++r){
        const int m = m0 + wr + mt*16 + lc*4 + r;
        const int n = n0 + wc + nt*16 + lr;
        float v = acc[mt][nt][r];
        if (EPI == 0){
          Cout[(size_t)m * Ndim + n] = v;
        } else {
          const int t = n >> 10, rem = n & 1023, hh = rem >> 6, d = rem & 63;
          const int b = m >> 11, s = m & 2047;
          const int bh = b * H_NUM + hh;
          if (t == 0) v *= (0.125f * LOG2E);  // fold 1/sqrt(64) and log2(e) into Q
          size_t o;
          if (t == 2)  o = ((size_t)bh * D_DIM + d) * S_LEN + s;   // V transposed
          else         o = ((size_t)bh * S_LEN + s) * D_DIM + d;
          _Float16* ph = (t == 0) ? qh : (t == 1) ? kh : vh;
          ph[o] = (_Float16)v;
        }
      }
}

// ---------------- flash attention, transposed-QK in-register softmax ----------
// Grid 32x32, one q-tile per block. LDS = 16K(sK)+16K(sV)+8K(sP) = 40960 B
// exactly -> 4 blocks/CU. sP is unpadded [4][16][64] with XOR swizzle (writes
// and reads share the same XOR; pa reads are 2-lane/bank). XCD-aware remap
// keeps each XCD on 4 bh values; balanced qt permutation makes every CU's 4
// resident blocks sum to 66 KV-iterations.
__global__ __launch_bounds__(256, 4) void attn_kernel(
    const _Float16* __restrict__ Qh, const _Float16* __restrict__ Kh,
    const _Float16* __restrict__ Vth, _Float16* __restrict__ Ao)
{
  __shared__ __align__(16) _Float16 sK[2][64][64], sV[2][64][64];   // 32768 B
  __shared__ __align__(16) _Float16 sP[4][16][64];                  // 8192 B
  const int tid = threadIdx.x, wid = tid >> 6, lane = tid & 63;
  const int id  = blockIdx.x + 32 * blockIdx.y;
  const int xcd = id & 7, seq = id >> 3;
  const int bh  = xcd + 8 * (seq & 3);
  // balanced qt permutation: a CU's 4 blocks have bsel 0..3, same hsel; sum 62.
  const int g = seq >> 2, hsel = g & 7, bsel = g >> 3;
  const int qt = (bsel == 0) ? 31 - hsel
               : (bsel == 1) ? hsel
               : (bsel == 2) ? 23 - hsel
                             : 8 + hsel;
  const int q0 = qt * 64;
  const int nT = qt + 1;
  const int lr = lane & 15, lc = lane >> 4;
  const int swz = (lr & 7) << 4;        // byte XOR for swizzled LDS accesses
  const size_t base = (size_t)bh * S_LEN * D_DIM;

  // staging geometry: wave w stages chunks {2w,2w+1} (8 rows each) of K and V
  const int lrow = lane >> 3;                       // 0..7
  const int cswz = ((lane & 7) ^ lrow) * 8;         // inverse-swizzled source col (halfs)

  auto stage = [&](int t, int b){
    const int kv0 = t * 64;
#pragma unroll
    for (int cc = 0; cc < 2; ++cc){
      const int c = wid * 2 + cc;
      const int row = c * 8 + lrow;
      gload_lds16(&Kh[base + (size_t)(kv0 + row) * D_DIM + cswz], &sK[b][c*8][0]);
      gload_lds16(&Vth[base + (size_t)row * S_LEN + kv0 + cswz], &sV[b][c*8][0]);
    }
  };

  const int b = bh >> 4, hh = bh & 15;

  // Q fragments (B-operand), hoisted; Q already scaled by log2e/8
  half8 fq[2];
  {
    const int qrow = q0 + wid*16 + lr;
#pragma unroll
    for (int kc = 0; kc < 2; ++kc)
      fq[kc] = *reinterpret_cast<const half8*>(&Qh[base + (size_t)qrow * 64 + kc*32 + lc*8]);
  }

  f32x4 acc[4] = {};
  float m = -1e30f, l = 0.f, tm = -1e30f;   // per-lane stats for q = lr

  stage(0, 0);
  __syncthreads();

  int cur = 0;
  for (int t = 0; t < nT; ++t){
    if (t + 1 < nT) stage(t + 1, cur ^ 1);   // async loads hide under compute

    // ST = K·Q^T: lane holds q=lr (col), k = nt*16 + lc*4 + r (row)
    const char* kb = (const char*)&sK[cur][0][0];
    f32x4 sc[4];
    __builtin_amdgcn_s_setprio(1);
#pragma unroll
    for (int nt = 0; nt < 4; ++nt){
      f32x4 z = {};
#pragma unroll
      for (int kc = 0; kc < 2; ++kc){
        const half8 fk = *reinterpret_cast<const half8*>(
            kb + (nt*16 + lr)*128 + ((kc*64 + lc*16) ^ swz));
        z = MFMA16(fk, fq[kc], z);
      }
      sc[nt] = z;
    }
    __builtin_amdgcn_s_setprio(0);

    if (t == qt){   // diagonal: mask k > q
#pragma unroll
      for (int nt = 0; nt < 4; ++nt)
#pragma unroll
        for (int r = 0; r < 4; ++r)
          if (nt*16 + lc*4 + r > wid*16 + lr) sc[nt][r] = -1e30f;
    }

    // in-lane max over 16 + 2 cross-lane hops (lanes lr, lr+16, lr+32, lr+48)
    f32x4 a;
#pragma unroll
    for (int j = 0; j < 4; ++j)
      a[j] = fmaxf(fmaxf(sc[0][j], sc[1][j]), fmaxf(sc[2][j], sc[3][j]));
    float mx = fmaxf(fmaxf(a[0], a[1]), fmaxf(a[2], a[3]));
    mx = fmaxf(mx, __shfl_xor(mx, 16));
    mx = fmaxf(mx, __shfl_xor(mx, 32));
    tm = fmaxf(tm, mx);

    if (__any(mx > m + 8.0f)){   // defer-max THR=8 (log2 units)
      const float mn = fmaxf(m, mx);
      const float s = exp2_fast(m - mn);
      l *= s; m = mn;
      float rs[4];
#pragma unroll
      for (int r = 0; r < 4; ++r)
        rs[r] = __shfl(s, (lc << 4) | (lc*4 + r), 64);
#pragma unroll
      for (int dt = 0; dt < 4; ++dt)
#pragma unroll
        for (int r = 0; r < 4; ++r) acc[dt][r] *= rs[r];
    }

    // P = exp2(sc - m); in-lane sum + 2 hops
    f32x4 ssum = {};
#pragma unroll
    for (int nt = 0; nt < 4; ++nt){
#pragma unroll
      for (int r = 0; r < 4; ++r) sc[nt][r] = exp2_fast(sc[nt][r] - m);
      ssum += sc[nt];
    }
    float s1 = (ssum[0] + ssum[1]) + (ssum[2] + ssum[3]);
    s1 += __shfl_xor(s1, 16);
    s1 += __shfl_xor(s1, 32);
    l += s1;

    // pack P -> per-wave swizzled LDS tile (row q=lr, unswizzled byte k*2)
    char* pw = (char*)&sP[wid][0][0];
#pragma unroll
    for (int nt = 0; nt < 4; ++nt){
      int2 pk;
      pk.x = __builtin_bit_cast(int, __builtin_amdgcn_cvt_pkrtz(sc[nt][0], sc[nt][1]));
      pk.y = __builtin_bit_cast(int, __builtin_amdgcn_cvt_pkrtz(sc[nt][2], sc[nt][3]));
      *reinterpret_cast<int2*>(pw + lr*128 + ((nt*32 + lc*8) ^ swz)) = pk;
    }

    // PV A-fragment: row q=lr, k = kc*32 + lc*8 + j (same XOR as the writes)
    const half8 pa0 = *reinterpret_cast<const half8*>(pw + lr*128 + ((lc*16) ^ swz));
    const half8 pa1 = *reinterpret_cast<const half8*>(pw + lr*128 + ((64 + lc*16) ^ swz));
    const char* vb = (const char*)&sV[cur][0][0];
    __builtin_amdgcn_s_setprio(1);
#pragma unroll
    for (int dt = 0; dt < 4; ++dt){
#pragma unroll
      for (int kc = 0; kc < 2; ++kc){
        const half8 fv = *reinterpret_cast<const half8*>(
            vb + (dt*16 + lr)*128 + ((kc*64 + lc*16) ^ swz));
        acc[dt] = MFMA16(kc ? pa1 : pa0, fv, acc[dt]);
      }
    }
    __builtin_amdgcn_s_setprio(0);

    __syncthreads();   // drains staging vmcnt; guards buffer swap + sP reuse
    cur ^= 1;
  }

  // finalize: ghost term = 2^(truemax - m); denom broadcast per q-row
  const float den = l + exp2_fast(tm - m);
  float rden[4];
#pragma unroll
  for (int r = 0; r < 4; ++r)
    rden[r] = __shfl(den, (lc << 4) | (lc*4 + r), 64);
#pragma unroll
  for (int dt = 0; dt < 4; ++dt)
#pragma unroll
    for (int r = 0; r < 4; ++r){
      const float o = acc[dt][r] / rden[r];
      const int q = q0 + wid*16 + lc*4 + r;
      const int d = dt*16 + lr;
      Ao[((size_t)(b*S_LEN + q)) * E_DIM + hh*D_DIM + d] = (_Float16)o;
    }
}

// ---------------- launch ----------------
extern "C" void kernel_launch(void* const* d_in, const int* in_sizes, int n_in,
                              void* d_out, int out_size, void* d_ws, size_t ws_size,
                              hipStream_t stream){
  const float* X    = (const float*)d_in[0];
  const float* Wqkv = (const float*)d_in[1];
  const float* Wo   = (const float*)d_in[2];
  float* out = (float*)d_out;

  _Float16* w = (_Float16*)d_ws;
  size_t off = 0;
  auto alloc = [&](size_t n){ _Float16* p = w + off; off += n; return p; };
  const size_t ME   = (size_t)M_ROWS * E_DIM;
  const size_t WQ   = (size_t)N3 * E_DIM;
  const size_t WOsz = (size_t)E_DIM * E_DIM;
  const size_t QK   = (size_t)NBH * S_LEN * D_DIM;
  _Float16 *Xh = alloc(ME);
  _Float16 *Wqh = alloc(WQ);
  _Float16 *Woh = alloc(WOsz);
  _Float16 *Qh = alloc(QK), *Kh = alloc(QK), *Vth = alloc(QK);
  _Float16 *Ahalf = alloc(ME);

  cast_x_kernel<<<(int)(ME/4/256), 256, 0, stream>>>(X, Xh, (int)(ME/4));
  transpose_half<<<dim3(N3/32, E_DIM/32), 256, 0, stream>>>(Wqkv, Wqh, E_DIM, N3);
  transpose_half<<<dim3(E_DIM/32, E_DIM/32), 256, 0, stream>>>(Wo, Woh, E_DIM, E_DIM);

  gemm97<1><<<dim3(N3/128, M_ROWS/128), 256, 0, stream>>>(
      Xh, Wqh, E_DIM, N3, nullptr, Qh, Kh, Vth);

  attn_kernel<<<dim3(32, NBH), 256, 0, stream>>>(Qh, Kh, Vth, Ahalf);

  gemm97<0><<<dim3(E_DIM/128, M_ROWS/128), 256, 0, stream>>>(
      Ahalf, Woh, E_DIM, E_DIM, out, nullptr, nullptr, nullptr);
}

// Round 13
// 119.418 us; speedup vs baseline: 1.0430x; 1.0408x over previous
//
#include <hip/hip_runtime.h>

typedef float    f32x4  __attribute__((ext_vector_type(4)));
typedef _Float16 half8  __attribute__((ext_vector_type(8)));
typedef _Float16 half4v __attribute__((ext_vector_type(4)));

#define MFMA16(a,b,c) __builtin_amdgcn_mfma_f32_16x16x32_f16(a,b,c,0,0,0)

__device__ __forceinline__ float exp2_fast(float x){
  float y; asm("v_exp_f32 %0, %1" : "=v"(y) : "v"(x)); return y;
}
// async global->LDS, 16B per lane; LDS dest is wave-uniform base + lane*16
__device__ __forceinline__ void gload_lds16(const _Float16* g, _Float16* l){
  __builtin_amdgcn_global_load_lds(
      (const __attribute__((address_space(1))) unsigned int*)(g),
      (__attribute__((address_space(3))) unsigned int*)(l),
      16, 0, 0);
}

#define S_LEN 2048
#define E_DIM 1024
#define H_NUM 16
#define D_DIM 64
#define NBH   32
#define M_ROWS 4096
#define N3    3072
#define LOG2E 1.44269504089f

// ---------------- prep: fp32 -> fp16 cast ----------------
__global__ void cast_x_kernel(const float* __restrict__ in,
                              _Float16* __restrict__ hi, int n4){
  int i = blockIdx.x * 256 + threadIdx.x;
  if (i >= n4) return;
  const float4 v = reinterpret_cast<const float4*>(in)[i];
  half4v h;
  h[0] = (_Float16)v.x; h[1] = (_Float16)v.y;
  h[2] = (_Float16)v.z; h[3] = (_Float16)v.w;
  *reinterpret_cast<half4v*>(&hi[i*4]) = h;
}

// out[n][k] = in[k][n], single fp16. in is R x C, out is C x R.
__global__ void transpose_half(const float* __restrict__ in,
                               _Float16* __restrict__ hi, int R, int C){
  __shared__ float tile[32][33];
  int bx = blockIdx.x * 32, by = blockIdx.y * 32;
  int tx = threadIdx.x & 31, ty = threadIdx.x >> 5;   // 256 threads = 32x8
#pragma unroll
  for (int i = ty; i < 32; i += 8)
    tile[i][tx] = in[(size_t)(by + i) * C + bx + tx];
  __syncthreads();
#pragma unroll
  for (int i = ty; i < 32; i += 8)
    hi[(size_t)(bx + i) * R + by + tx] = (_Float16)tile[tx][i];
}

// ---------------- fp16 GEMM (m97 structure + T2 swizzle), 128x128 ----------
// C = A @ B^T(rowmajor N x K). global_load_lds staging; linear LDS dest,
// inverse-XOR-swizzled global source col, XOR-swizzled reads (rule #21).
// EPI=1: scatter qkv -> Q(*log2e/8)[bh][s][d], K[bh][s][d], V^T[bh][d][s].
template<int EPI>
__global__ __launch_bounds__(256, 3) void gemm97(
    const _Float16* __restrict__ A, const _Float16* __restrict__ B,
    int Kdim, int Ndim, float* __restrict__ Cout,
    _Float16* __restrict__ qh, _Float16* __restrict__ kh, _Float16* __restrict__ vh)
{
  __shared__ __align__(16) _Float16 sA[128][64], sB[128][64];
  const int tid = threadIdx.x;
  const int m0 = blockIdx.y * 128, n0 = blockIdx.x * 128;
  const int wid = tid >> 6, lane = tid & 63;
  const int wr = (wid >> 1) * 64, wc = (wid & 1) * 64;
  const int lr = lane & 15, lc = lane >> 4;
  const int ldrow = lane >> 3;                        // 0..7 within chunk
  const int ldcol = ((lane & 7) ^ ldrow) * 8;         // inverse-swizzled source col
  const int swz = (lr & 7) << 4;                      // byte XOR for reads

  f32x4 acc[4][4] = {};
  const int nK = Kdim >> 6;
  for (int ks = 0; ks < nK; ++ks){
    const int k0 = ks << 6;
#pragma unroll
    for (int cc = 0; cc < 4; ++cc){
      const int c = wid * 4 + cc;
      const int row = c * 8 + ldrow;
      gload_lds16(&A[(size_t)(m0 + row) * Kdim + k0 + ldcol], &sA[c*8][0]);
      gload_lds16(&B[(size_t)(n0 + row) * Kdim + k0 + ldcol], &sB[c*8][0]);
    }
    __syncthreads();
    const char* ab = (const char*)&sA[0][0];
    const char* bb = (const char*)&sB[0][0];
#pragma unroll
    for (int kk = 0; kk < 64; kk += 32){
      half8 fa[4], fb[4];
#pragma unroll
      for (int t = 0; t < 4; ++t){
        fa[t] = *reinterpret_cast<const half8*>(
            ab + (wr + t*16 + lr)*128 + ((kk*2 + lc*16) ^ swz));
        fb[t] = *reinterpret_cast<const half8*>(
            bb + (wc + t*16 + lr)*128 + ((kk*2 + lc*16) ^ swz));
      }
#pragma unroll
      for (int mt = 0; mt < 4; ++mt)
#pragma unroll
        for (int nt = 0; nt < 4; ++nt)
          acc[mt][nt] = MFMA16(fa[mt], fb[nt], acc[mt][nt]);
    }
    __syncthreads();
  }
#pragma unroll
  for (int mt = 0; mt < 4; ++mt)
#pragma unroll
    for (int nt = 0; nt < 4; ++nt)
#pragma unroll
      for (int r = 0; r < 4; ++r){
        const int m = m0 + wr + mt*16 + lc*4 + r;
        const int n = n0 + wc + nt*16 + lr;
        float v = acc[mt][nt][r];
        if (EPI == 0){
          Cout[(size_t)m * Ndim + n] = v;
        } else {
          const int t = n >> 10, rem = n & 1023, hh = rem >> 6, d = rem & 63;
          const int b = m >> 11, s = m & 2047;
          const int bh = b * H_NUM + hh;
          if (t == 0) v *= (0.125f * LOG2E);  // fold 1/sqrt(64) and log2(e) into Q
          size_t o;
          if (t == 2)  o = ((size_t)bh * D_DIM + d) * S_LEN + s;   // V transposed
          else         o = ((size_t)bh * S_LEN + s) * D_DIM + d;
          _Float16* ph = (t == 0) ? qh : (t == 1) ? kh : vh;
          ph[o] = (_Float16)v;
        }
      }
}

// ---------------- fp16 GEMM, 64x128 tile (occupancy variant for GEMM2) -----
__global__ __launch_bounds__(256, 4) void gemm64(
    const _Float16* __restrict__ A, const _Float16* __restrict__ B,
    int Kdim, int Ndim, float* __restrict__ Cout)
{
  __shared__ __align__(16) _Float16 sA[64][64], sB[128][64];
  const int tid = threadIdx.x;
  const int m0 = blockIdx.y * 64, n0 = blockIdx.x * 128;
  const int wid = tid >> 6, lane = tid & 63;
  const int wr = (wid >> 1) * 32, wc = (wid & 1) * 64;
  const int lr = lane & 15, lc = lane >> 4;
  const int ldrow = lane >> 3;
  const int ldcol = ((lane & 7) ^ ldrow) * 8;
  const int swz = (lr & 7) << 4;

  f32x4 acc[2][4] = {};
  const int nK = Kdim >> 6;
  for (int ks = 0; ks < nK; ++ks){
    const int k0 = ks << 6;
#pragma unroll
    for (int cc = 0; cc < 2; ++cc){
      const int c = wid * 2 + cc;
      const int row = c * 8 + ldrow;
      gload_lds16(&A[(size_t)(m0 + row) * Kdim + k0 + ldcol], &sA[c*8][0]);
    }
#pragma unroll
    for (int cc = 0; cc < 4; ++cc){
      const int c = wid * 4 + cc;
      const int row = c * 8 + ldrow;
      gload_lds16(&B[(size_t)(n0 + row) * Kdim + k0 + ldcol], &sB[c*8][0]);
    }
    __syncthreads();
    const char* ab = (const char*)&sA[0][0];
    const char* bb = (const char*)&sB[0][0];
#pragma unroll
    for (int kk = 0; kk < 64; kk += 32){
      half8 fa[2], fb[4];
#pragma unroll
      for (int t = 0; t < 2; ++t)
        fa[t] = *reinterpret_cast<const half8*>(
            ab + (wr + t*16 + lr)*128 + ((kk*2 + lc*16) ^ swz));
#pragma unroll
      for (int t = 0; t < 4; ++t)
        fb[t] = *reinterpret_cast<const half8*>(
            bb + (wc + t*16 + lr)*128 + ((kk*2 + lc*16) ^ swz));
#pragma unroll
      for (int mt = 0; mt < 2; ++mt)
#pragma unroll
        for (int nt = 0; nt < 4; ++nt)
          acc[mt][nt] = MFMA16(fa[mt], fb[nt], acc[mt][nt]);
    }
    __syncthreads();
  }
#pragma unroll
  for (int mt = 0; mt < 2; ++mt)
#pragma unroll
    for (int nt = 0; nt < 4; ++nt)
#pragma unroll
      for (int r = 0; r < 4; ++r){
        const int m = m0 + wr + mt*16 + lc*4 + r;
        const int n = n0 + wc + nt*16 + lr;
        Cout[(size_t)m * Ndim + n] = acc[mt][nt][r];
      }
}

// ---------------- flash attention, transposed-QK in-register softmax ----------
// Grid 32x32, one q-tile per block. LDS = 16K(sK dbuf) + 8K(sV single) + 8K(sP)
// = 32768 B -> 4-5 blocks/CU. V(t) staged at top of iter t (latency hidden
// under QK+softmax); own-wave counted vmcnt + raw s_barrier before PV makes
// all waves' V visible without draining the K prefetch. XCD-aware remap +
// balanced qt permutation (every CU's 4 blocks sum to 66 KV-iterations).
__global__ __launch_bounds__(256, 4) void attn_kernel(
    const _Float16* __restrict__ Qh, const _Float16* __restrict__ Kh,
    const _Float16* __restrict__ Vth, _Float16* __restrict__ Ao)
{
  __shared__ __align__(16) _Float16 sK[2][64][64];   // 16384 B
  __shared__ __align__(16) _Float16 sV[64][64];      //  8192 B
  __shared__ __align__(16) _Float16 sP[4][16][64];   //  8192 B
  const int tid = threadIdx.x, wid = tid >> 6, lane = tid & 63;
  const int id  = blockIdx.x + 32 * blockIdx.y;
  const int xcd = id & 7, seq = id >> 3;
  const int bh  = xcd + 8 * (seq & 3);
  // balanced qt permutation: a CU's 4 blocks have bsel 0..3, same hsel; sum 62.
  const int g = seq >> 2, hsel = g & 7, bsel = g >> 3;
  const int qt = (bsel == 0) ? 31 - hsel
               : (bsel == 1) ? hsel
               : (bsel == 2) ? 23 - hsel
                             : 8 + hsel;
  const int q0 = qt * 64;
  const int nT = qt + 1;
  const int lr = lane & 15, lc = lane >> 4;
  const int swz = (lr & 7) << 4;        // byte XOR for swizzled LDS accesses
  const size_t base = (size_t)bh * S_LEN * D_DIM;

  // staging geometry: wave w stages chunks {2w,2w+1} (8 rows each)
  const int lrow = lane >> 3;                       // 0..7
  const int cswz = ((lane & 7) ^ lrow) * 8;         // inverse-swizzled source col (halfs)

  auto stageK = [&](int t, int b){
    const int kv0 = t * 64;
#pragma unroll
    for (int cc = 0; cc < 2; ++cc){
      const int c = wid * 2 + cc;
      const int row = c * 8 + lrow;
      gload_lds16(&Kh[base + (size_t)(kv0 + row) * D_DIM + cswz], &sK[b][c*8][0]);
    }
  };
  auto stageV = [&](int t){
    const int kv0 = t * 64;
#pragma unroll
    for (int cc = 0; cc < 2; ++cc){
      const int c = wid * 2 + cc;
      const int row = c * 8 + lrow;
      gload_lds16(&Vth[base + (size_t)row * S_LEN + kv0 + cswz], &sV[c*8][0]);
    }
  };

  const int b = bh >> 4, hh = bh & 15;

  // Q fragments (B-operand), hoisted; Q already scaled by log2e/8
  half8 fq[2];
  {
    const int qrow = q0 + wid*16 + lr;
#pragma unroll
    for (int kc = 0; kc < 2; ++kc)
      fq[kc] = *reinterpret_cast<const half8*>(&Qh[base + (size_t)qrow * 64 + kc*32 + lc*8]);
  }

  f32x4 acc[4] = {};
  float m = -1e30f, l = 0.f, tm = -1e30f;   // per-lane stats for q = lr

  stageK(0, 0);
  __syncthreads();

  int cur = 0;
  for (int t = 0; t < nT; ++t){
    stageV(t);                               // V for THIS iteration (2 loads, oldest)
    if (t + 1 < nT) stageK(t + 1, cur ^ 1);  // K prefetch (2 loads, newest)

    // ST = K·Q^T: lane holds q=lr (col), k = nt*16 + lc*4 + r (row)
    const char* kb = (const char*)&sK[cur][0][0];
    f32x4 sc[4];
    __builtin_amdgcn_s_setprio(1);
#pragma unroll
    for (int nt = 0; nt < 4; ++nt){
      f32x4 z = {};
#pragma unroll
      for (int kc = 0; kc < 2; ++kc){
        const half8 fk = *reinterpret_cast<const half8*>(
            kb + (nt*16 + lr)*128 + ((kc*64 + lc*16) ^ swz));
        z = MFMA16(fk, fq[kc], z);
      }
      sc[nt] = z;
    }
    __builtin_amdgcn_s_setprio(0);

    if (t == qt){   // diagonal: mask k > q
#pragma unroll
      for (int nt = 0; nt < 4; ++nt)
#pragma unroll
        for (int r = 0; r < 4; ++r)
          if (nt*16 + lc*4 + r > wid*16 + lr) sc[nt][r] = -1e30f;
    }

    // in-lane max over 16 + 2 cross-lane hops (lanes lr, lr+16, lr+32, lr+48)
    f32x4 a;
#pragma unroll
    for (int j = 0; j < 4; ++j)
      a[j] = fmaxf(fmaxf(sc[0][j], sc[1][j]), fmaxf(sc[2][j], sc[3][j]));
    float mx = fmaxf(fmaxf(a[0], a[1]), fmaxf(a[2], a[3]));
    mx = fmaxf(mx, __shfl_xor(mx, 16));
    mx = fmaxf(mx, __shfl_xor(mx, 32));
    tm = fmaxf(tm, mx);

    if (__any(mx > m + 8.0f)){   // defer-max THR=8 (log2 units)
      const float mn = fmaxf(m, mx);
      const float s = exp2_fast(m - mn);
      l *= s; m = mn;
      float rs[4];
#pragma unroll
      for (int r = 0; r < 4; ++r)
        rs[r] = __shfl(s, (lc << 4) | (lc*4 + r), 64);
#pragma unroll
      for (int dt = 0; dt < 4; ++dt)
#pragma unroll
        for (int r = 0; r < 4; ++r) acc[dt][r] *= rs[r];
    }

    // P = exp2(sc - m); in-lane sum + 2 hops
    f32x4 ssum = {};
#pragma unroll
    for (int nt = 0; nt < 4; ++nt){
#pragma unroll
      for (int r = 0; r < 4; ++r) sc[nt][r] = exp2_fast(sc[nt][r] - m);
      ssum += sc[nt];
    }
    float s1 = (ssum[0] + ssum[1]) + (ssum[2] + ssum[3]);
    s1 += __shfl_xor(s1, 16);
    s1 += __shfl_xor(s1, 32);
    l += s1;

    // pack P -> per-wave swizzled LDS tile (row q=lr)
    char* pw = (char*)&sP[wid][0][0];
#pragma unroll
    for (int nt = 0; nt < 4; ++nt){
      int2 pk;
      pk.x = __builtin_bit_cast(int, __builtin_amdgcn_cvt_pkrtz(sc[nt][0], sc[nt][1]));
      pk.y = __builtin_bit_cast(int, __builtin_amdgcn_cvt_pkrtz(sc[nt][2], sc[nt][3]));
      *reinterpret_cast<int2*>(pw + lr*128 + ((nt*32 + lc*8) ^ swz)) = pk;
    }

    // PV A-fragment: row q=lr, k = kc*32 + lc*8 + j (same XOR as the writes)
    const half8 pa0 = *reinterpret_cast<const half8*>(pw + lr*128 + ((lc*16) ^ swz));
    const half8 pa1 = *reinterpret_cast<const half8*>(pw + lr*128 + ((64 + lc*16) ^ swz));

    // own V loads are the 2 oldest vmem ops -> counted wait keeps K in flight;
    // raw s_barrier makes every wave's V visible before PV.
    if (t + 1 < nT) asm volatile("s_waitcnt vmcnt(2)" ::: "memory");
    else            asm volatile("s_waitcnt vmcnt(0)" ::: "memory");
    __builtin_amdgcn_sched_barrier(0);
    __builtin_amdgcn_s_barrier();

    const char* vb = (const char*)&sV[0][0];
    __builtin_amdgcn_s_setprio(1);
#pragma unroll
    for (int dt = 0; dt < 4; ++dt){
#pragma unroll
      for (int kc = 0; kc < 2; ++kc){
        const half8 fv = *reinterpret_cast<const half8*>(
            vb + (dt*16 + lr)*128 + ((kc*64 + lc*16) ^ swz));
        acc[dt] = MFMA16(kc ? pa1 : pa0, fv, acc[dt]);
      }
    }
    __builtin_amdgcn_s_setprio(0);

    __syncthreads();   // publishes sK[back]; guards sV overwrite + sP reuse
    cur ^= 1;
  }

  // finalize: ghost term = 2^(truemax - m); denom broadcast per q-row
  const float den = l + exp2_fast(tm - m);
  float rden[4];
#pragma unroll
  for (int r = 0; r < 4; ++r)
    rden[r] = __shfl(den, (lc << 4) | (lc*4 + r), 64);
#pragma unroll
  for (int dt = 0; dt < 4; ++dt)
#pragma unroll
    for (int r = 0; r < 4; ++r){
      const float o = acc[dt][r] / rden[r];
      const int q = q0 + wid*16 + lc*4 + r;
      const int d = dt*16 + lr;
      Ao[((size_t)(b*S_LEN + q)) * E_DIM + hh*D_DIM + d] = (_Float16)o;
    }
}

// ---------------- launch ----------------
extern "C" void kernel_launch(void* const* d_in, const int* in_sizes, int n_in,
                              void* d_out, int out_size, void* d_ws, size_t ws_size,
                              hipStream_t stream){
  const float* X    = (const float*)d_in[0];
  const float* Wqkv = (const float*)d_in[1];
  const float* Wo   = (const float*)d_in[2];
  float* out = (float*)d_out;

  _Float16* w = (_Float16*)d_ws;
  size_t off = 0;
  auto alloc = [&](size_t n){ _Float16* p = w + off; off += n; return p; };
  const size_t ME   = (size_t)M_ROWS * E_DIM;
  const size_t WQ   = (size_t)N3 * E_DIM;
  const size_t WOsz = (size_t)E_DIM * E_DIM;
  const size_t QK   = (size_t)NBH * S_LEN * D_DIM;
  _Float16 *Xh = alloc(ME);
  _Float16 *Wqh = alloc(WQ);
  _Float16 *Woh = alloc(WOsz);
  _Float16 *Qh = alloc(QK), *Kh = alloc(QK), *Vth = alloc(QK);
  _Float16 *Ahalf = alloc(ME);

  cast_x_kernel<<<(int)(ME/4/256), 256, 0, stream>>>(X, Xh, (int)(ME/4));
  transpose_half<<<dim3(N3/32, E_DIM/32), 256, 0, stream>>>(Wqkv, Wqh, E_DIM, N3);
  transpose_half<<<dim3(E_DIM/32, E_DIM/32), 256, 0, stream>>>(Wo, Woh, E_DIM, E_DIM);

  gemm97<1><<<dim3(N3/128, M_ROWS/128), 256, 0, stream>>>(
      Xh, Wqh, E_DIM, N3, nullptr, Qh, Kh, Vth);

  attn_kernel<<<dim3(32, NBH), 256, 0, stream>>>(Qh, Kh, Vth, Ahalf);

  gemm64<<<dim3(E_DIM/128, M_ROWS/64), 256, 0, stream>>>(
      Ahalf, Woh, E_DIM, E_DIM, out);
}